// Round 1
// baseline (889.635 us; speedup 1.0000x reference)
//
#include <hip/hip_runtime.h>

#define N_PAT 100000
#define BDIM  1024
#define DDIM  256

typedef float f32x4 __attribute__((ext_vector_type(4)));
typedef short s16x8 __attribute__((ext_vector_type(8)));

__device__ __forceinline__ unsigned short f2bf(float x) {
    unsigned int u = __float_as_uint(x);
    return (unsigned short)((u + 0x7FFFu + ((u >> 16) & 1u)) >> 16);
}

// Swizzled byte offset in an LDS tile with 128-byte rows (64 bf16/row).
__device__ __forceinline__ int ofs128(int row, int byteInRow) {
    return row * 128 + (byteInRow ^ ((row & 7) << 4));
}
// Swizzled byte offset in an LDS tile with 512-byte rows (256 bf16/row).
__device__ __forceinline__ int ofs512(int row, int byteInRow) {
    return row * 512 + (byteInRow ^ ((row & 7) << 4));
}

// ---------------- prep kernels ----------------

__global__ __launch_bounds__(256) void k_prep_pat(const float* __restrict__ pat,
                                                  unsigned short* __restrict__ patbf) {
    // 25.6M elems, 8 per iteration
    long total = (long)N_PAT * DDIM / 8;
    long stride = (long)gridDim.x * blockDim.x;
    for (long g = (long)blockIdx.x * blockDim.x + threadIdx.x; g < total; g += stride) {
        const float4* s = (const float4*)(pat + g * 8);
        float4 a = s[0], b = s[1];
        s16x8 o;
        o[0] = (short)f2bf(a.x); o[1] = (short)f2bf(a.y);
        o[2] = (short)f2bf(a.z); o[3] = (short)f2bf(a.w);
        o[4] = (short)f2bf(b.x); o[5] = (short)f2bf(b.y);
        o[6] = (short)f2bf(b.z); o[7] = (short)f2bf(b.w);
        *(s16x8*)(patbf + g * 8) = o;
    }
}

__global__ __launch_bounds__(256) void k_proj(const float* __restrict__ state,
                                              const float* __restrict__ W,
                                              unsigned short* __restrict__ projbf) {
    __shared__ float srow[DDIM];
    int b = blockIdx.x, t = threadIdx.x;
    srow[t] = state[b * DDIM + t];
    __syncthreads();
    const float4* s4 = (const float4*)srow;
    const float4* w4 = (const float4*)(W + (long)t * DDIM);
    float acc = 0.f;
#pragma unroll 8
    for (int k = 0; k < DDIM / 4; k++) {
        float4 sv = s4[k], wv = w4[k];
        acc += sv.x * wv.x + sv.y * wv.y + sv.z * wv.z + sv.w * wv.w;
    }
    projbf[b * DDIM + t] = f2bf(acc);
}

__global__ __launch_bounds__(256) void k_prep_nd(const float* __restrict__ depths,
                                                 const float* __restrict__ gate,
                                                 float* __restrict__ logdg,
                                                 int* __restrict__ Lbits) {
    int n = blockIdx.x * 256 + threadIdx.x;
    float v = 0.f;
    if (n < N_PAT) {
        float d = depths[n], g = gate[n];
        logdg[n] = __logf(fmaxf(d, 1e-8f)) + __logf(fmaxf(g, 1e-8f));
        v = log1pf(d);
    }
#pragma unroll
    for (int m = 1; m <= 32; m <<= 1) v = fmaxf(v, __shfl_xor(v, m));
    if ((threadIdx.x & 63) == 0) atomicMax(Lbits, __float_as_int(v));
}

// ---------------- pass A: row sums of exp(logits) ----------------
// grid (8 rowblocks, 128 chunks), 256 threads (4 waves, 2x2, wave tile 64x64)

__global__ __launch_bounds__(256, 3) void k_sums(const unsigned short* __restrict__ projbf,
                                                 const unsigned short* __restrict__ patbf,
                                                 const float* __restrict__ logdg,
                                                 float* __restrict__ lsum) {
    __shared__ unsigned short Ab[128 * 64];  // [m][k-chunk] rows 128B, swizzled
    __shared__ unsigned short Bb[128 * 64];  // [n][k-chunk] rows 128B, swizzled
    int rb = blockIdx.x, chunk = blockIdx.y;
    int t = threadIdx.x, lane = t & 63, wid = t >> 6;
    int wm = wid >> 1, wn = wid & 1;
    int lo = lane & 15, hi = lane >> 4;
    int mb = rb * 128;
    int NT = (N_PAT + 127) / 128;

    for (int tile = chunk; tile < NT; tile += gridDim.y) {
        int n0 = tile * 128;
        f32x4 acc[4][4];
#pragma unroll
        for (int i = 0; i < 4; i++)
#pragma unroll
            for (int j = 0; j < 4; j++) { acc[i][j][0] = 0.f; acc[i][j][1] = 0.f; acc[i][j][2] = 0.f; acc[i][j][3] = 0.f; }

        for (int kc = 0; kc < 4; kc++) {
            // stage A chunk [128][64]
#pragma unroll
            for (int r = 0; r < 4; r++) {
                int id = t + r * 256;
                int row = id >> 3, slot = id & 7;
                uint4 v = *(const uint4*)(projbf + (mb + row) * DDIM + kc * 64 + slot * 8);
                *(uint4*)((char*)Ab + ofs128(row, slot * 16)) = v;
            }
            // stage B chunk [128][64]
#pragma unroll
            for (int r = 0; r < 4; r++) {
                int id = t + r * 256;
                int row = id >> 3, slot = id & 7;
                int pn = n0 + row;
                uint4 v = {0u, 0u, 0u, 0u};
                if (pn < N_PAT) v = *(const uint4*)(patbf + (long)pn * DDIM + kc * 64 + slot * 8);
                *(uint4*)((char*)Bb + ofs128(row, slot * 16)) = v;
            }
            __syncthreads();
#pragma unroll
            for (int ks = 0; ks < 2; ks++) {
                int kb = ks * 64 + hi * 16;
                s16x8 af[4], bq[4];
#pragma unroll
                for (int mf = 0; mf < 4; mf++)
                    af[mf] = *(const s16x8*)((const char*)Ab + ofs128(wm * 64 + mf * 16 + lo, kb));
#pragma unroll
                for (int nf = 0; nf < 4; nf++)
                    bq[nf] = *(const s16x8*)((const char*)Bb + ofs128(wn * 64 + nf * 16 + lo, kb));
#pragma unroll
                for (int mf = 0; mf < 4; mf++)
#pragma unroll
                    for (int nf = 0; nf < 4; nf++)
                        acc[mf][nf] = __builtin_amdgcn_mfma_f32_16x16x32_bf16(af[mf], bq[nf], acc[mf][nf], 0, 0, 0);
            }
            __syncthreads();
        }

        // epilogue: exp + row sums
        float ldg[4];
#pragma unroll
        for (int nf = 0; nf < 4; nf++) {
            int n = n0 + wn * 64 + nf * 16 + lo;
            ldg[nf] = (n < N_PAT) ? logdg[n] : -1e30f;
        }
#pragma unroll
        for (int mf = 0; mf < 4; mf++) {
            float rs[4] = {0.f, 0.f, 0.f, 0.f};
#pragma unroll
            for (int nf = 0; nf < 4; nf++)
#pragma unroll
                for (int r = 0; r < 4; r++)
                    rs[r] += __expf(acc[mf][nf][r] + ldg[nf]);
#pragma unroll
            for (int m = 1; m <= 8; m <<= 1)
#pragma unroll
                for (int r = 0; r < 4; r++) rs[r] += __shfl_xor(rs[r], m);
            if (lo == 0) {
                int rowb = mb + wm * 64 + mf * 16 + hi * 4;
#pragma unroll
                for (int r = 0; r < 4; r++) atomicAdd(&lsum[rowb + r], rs[r]);
            }
        }
    }
}

// ---------------- pass B: recompute sims, w = exp(logit - c), PV GEMM, col max ----------------
// grid (8 rowblocks, 64 chunks), 512 threads (8 waves)
// sims roles: wm4 = wid>>1 (rows, 32 each), wn2 = wid&1 (cols, 32 each); wave tile 32x32
// PV roles:   wm2 = wid>>2 (m half, 64 each), wd4 = wid&3 (d quarter, 64 each); wave tile 64d x 64m

__global__ __launch_bounds__(512, 2) void k_retrieve(const unsigned short* __restrict__ projbf,
                                                     const unsigned short* __restrict__ patbf,
                                                     const float* __restrict__ logdg,
                                                     const float* __restrict__ lsum,
                                                     int* __restrict__ maxwb,
                                                     float* __restrict__ outR) {
    __shared__ unsigned short Bf[64 * 256];  // patterns tile [n][k] rows 512B, swizzled
    __shared__ unsigned short AW[128 * 64];  // A-chunk, then w-tile [m][n], rows 128B, swizzled
    __shared__ unsigned short PT[256 * 64];  // transposed patterns [d][n], rows 128B, swizzled
    int rb = blockIdx.x, chunk = blockIdx.y;
    int t = threadIdx.x, lane = t & 63, wid = t >> 6;
    int wm4 = wid >> 1, wn2 = wid & 1;
    int wm2 = wid >> 2, wd4 = wid & 3;
    int lo = lane & 15, hi = lane >> 4;
    int mb = rb * 128;

    // preload per-row log-normalizers c = log(lsum)
    float c8[2][4];
#pragma unroll
    for (int mf = 0; mf < 2; mf++)
#pragma unroll
        for (int r = 0; r < 4; r++)
            c8[mf][r] = __logf(lsum[mb + wm4 * 32 + mf * 16 + hi * 4 + r]);

    f32x4 oacc[4][4];  // [df][mf] O^T accumulator, persists over tiles
#pragma unroll
    for (int i = 0; i < 4; i++)
#pragma unroll
        for (int j = 0; j < 4; j++) { oacc[i][j][0] = 0.f; oacc[i][j][1] = 0.f; oacc[i][j][2] = 0.f; oacc[i][j][3] = 0.f; }

    int NT = (N_PAT + 63) / 64;
    for (int tile = chunk; tile < NT; tile += gridDim.y) {
        int n0 = tile * 64;
        // stage Bf [64][256]
#pragma unroll
        for (int r = 0; r < 4; r++) {
            int id = t + r * 512;
            int row = id >> 5, slot = id & 31;
            int pn = n0 + row;
            uint4 v = {0u, 0u, 0u, 0u};
            if (pn < N_PAT) v = *(const uint4*)(patbf + (long)pn * DDIM + slot * 8);
            *(uint4*)((char*)Bf + ofs512(row, slot * 16)) = v;
        }
        __syncthreads();
        // transpose Bf -> PT (each wave handles k-groups wid*4 .. wid*4+3)
#pragma unroll
        for (int i = 0; i < 4; i++) {
            int kc8 = wid * 4 + i;
            s16x8 v = *(const s16x8*)((const char*)Bf + ofs512(lane, kc8 * 16));
#pragma unroll
            for (int e = 0; e < 8; e++) {
                int d = kc8 * 8 + e;
                *(unsigned short*)((char*)PT + ofs128(d, lane * 2)) = (unsigned short)v[e];
            }
        }
        // sims
        f32x4 facc[2][2];
#pragma unroll
        for (int i = 0; i < 2; i++)
#pragma unroll
            for (int j = 0; j < 2; j++) { facc[i][j][0] = 0.f; facc[i][j][1] = 0.f; facc[i][j][2] = 0.f; facc[i][j][3] = 0.f; }

        for (int kc = 0; kc < 4; kc++) {
#pragma unroll
            for (int r = 0; r < 2; r++) {
                int id = t + r * 512;
                int row = id >> 3, slot = id & 7;
                uint4 v = *(const uint4*)(projbf + (mb + row) * DDIM + kc * 64 + slot * 8);
                *(uint4*)((char*)AW + ofs128(row, slot * 16)) = v;
            }
            __syncthreads();
#pragma unroll
            for (int ks = 0; ks < 2; ks++) {
                int kb = ks * 64 + hi * 16;
                int kbB = kc * 128 + ks * 64 + hi * 16;
                s16x8 af[2], bq[2];
#pragma unroll
                for (int mf = 0; mf < 2; mf++)
                    af[mf] = *(const s16x8*)((const char*)AW + ofs128(wm4 * 32 + mf * 16 + lo, kb));
#pragma unroll
                for (int nf = 0; nf < 2; nf++)
                    bq[nf] = *(const s16x8*)((const char*)Bf + ofs512(wn2 * 32 + nf * 16 + lo, kbB));
#pragma unroll
                for (int mf = 0; mf < 2; mf++)
#pragma unroll
                    for (int nf = 0; nf < 2; nf++)
                        facc[mf][nf] = __builtin_amdgcn_mfma_f32_16x16x32_bf16(af[mf], bq[nf], facc[mf][nf], 0, 0, 0);
            }
            __syncthreads();
        }

        // epilogue: weights, col-max, write w-tile (reuse AW)
        float wv[2][2][4];
#pragma unroll
        for (int nf = 0; nf < 2; nf++) {
            int n = n0 + wn2 * 32 + nf * 16 + lo;
            float lg = (n < N_PAT) ? logdg[n] : -1e30f;
#pragma unroll
            for (int mf = 0; mf < 2; mf++)
#pragma unroll
                for (int r = 0; r < 4; r++)
                    wv[mf][nf][r] = __expf(facc[mf][nf][r] + lg - c8[mf][r]);
        }
#pragma unroll
        for (int nf = 0; nf < 2; nf++) {
            float mx = 0.f;
#pragma unroll
            for (int mf = 0; mf < 2; mf++)
#pragma unroll
                for (int r = 0; r < 4; r++) mx = fmaxf(mx, wv[mf][nf][r]);
            mx = fmaxf(mx, __shfl_xor(mx, 16));
            mx = fmaxf(mx, __shfl_xor(mx, 32));
            if (lane < 16) {
                int n = n0 + wn2 * 32 + nf * 16 + lane;
                if (n < N_PAT) atomicMax(&maxwb[n], __float_as_int(mx));
            }
        }
#pragma unroll
        for (int mf = 0; mf < 2; mf++)
#pragma unroll
            for (int nf = 0; nf < 2; nf++)
#pragma unroll
                for (int r = 0; r < 4; r++) {
                    int m = wm4 * 32 + mf * 16 + hi * 4 + r;
                    int cn = wn2 * 32 + nf * 16 + lo;
                    *(unsigned short*)((char*)AW + ofs128(m, cn * 2)) = f2bf(wv[mf][nf][r]);
                }
        __syncthreads();
        // PV: O^T[d][m] += sum_n PT[d][n] * w[m][n]
#pragma unroll
        for (int ks = 0; ks < 2; ks++) {
            int nb = ks * 64 + hi * 16;
            s16x8 pa[4], pb[4];
#pragma unroll
            for (int df = 0; df < 4; df++)
                pa[df] = *(const s16x8*)((const char*)PT + ofs128(wd4 * 64 + df * 16 + lo, nb));
#pragma unroll
            for (int mf = 0; mf < 4; mf++)
                pb[mf] = *(const s16x8*)((const char*)AW + ofs128(wm2 * 64 + mf * 16 + lo, nb));
#pragma unroll
            for (int df = 0; df < 4; df++)
#pragma unroll
                for (int mf = 0; mf < 4; mf++)
                    oacc[df][mf] = __builtin_amdgcn_mfma_f32_16x16x32_bf16(pa[df], pb[mf], oacc[df][mf], 0, 0, 0);
        }
        __syncthreads();
    }

    // write O^T frags to retrieved[m][d] via atomics (chunks partition n, so sum)
#pragma unroll
    for (int df = 0; df < 4; df++)
#pragma unroll
        for (int mf = 0; mf < 4; mf++)
#pragma unroll
            for (int r = 0; r < 4; r++) {
                int d = wd4 * 64 + df * 16 + hi * 4 + r;
                int m = mb + wm2 * 64 + mf * 16 + lo;
                atomicAdd(outR + m * DDIM + d, oacc[df][mf][r]);
            }
}

// ---------------- new depths ----------------

__global__ __launch_bounds__(256) void k_nd(const float* __restrict__ depths,
                                            const int* __restrict__ maxwb,
                                            const int* __restrict__ Lbits,
                                            float* __restrict__ outD) {
    int n = blockIdx.x * 256 + threadIdx.x;
    if (n >= N_PAT) return;
    float d = depths[n];
    float mw = __int_as_float(maxwb[n]);
    float L = __int_as_float(*Lbits);
    float dom = log1pf(d) / fmaxf(L, 1e-8f);
    float add = (mw > 0.1f) ? (0.01f * (1.0f - 0.7f * dom) * mw) : 0.0f;
    outD[n] = d + add;
}

// ---------------- launch ----------------

extern "C" void kernel_launch(void* const* d_in, const int* in_sizes, int n_in,
                              void* d_out, int out_size, void* d_ws, size_t ws_size,
                              hipStream_t stream) {
    const float* state  = (const float*)d_in[0];
    const float* W      = (const float*)d_in[1];
    const float* pat    = (const float*)d_in[2];
    const float* depths = (const float*)d_in[3];
    const float* gate   = (const float*)d_in[4];
    float* out = (float*)d_out;

    char* ws = (char*)d_ws;
    unsigned short* patbf  = (unsigned short*)ws;                 // 51,200,000 B
    unsigned short* projbf = (unsigned short*)(ws + 51200000);    //    524,288 B
    float* lsum  = (float*)(ws + 51724288);                       //      4,096 B
    float* logdg = (float*)(ws + 51728384);                       //    400,000 B
    int*   maxwb = (int*)(ws + 52128384);                         //    400,000 B
    int*   Lbits = (int*)(ws + 52528384);                         //         16 B

    // zero: lsum + logdg(harmless) + maxwb + Lbits, and d_out (retrieved accumulated by atomics)
    hipMemsetAsync(ws + 51724288, 0, 804112, stream);
    hipMemsetAsync(d_out, 0, (size_t)out_size * 4, stream);

    k_prep_pat<<<2048, 256, 0, stream>>>(pat, patbf);
    k_proj<<<1024, 256, 0, stream>>>(state, W, projbf);
    k_prep_nd<<<(N_PAT + 255) / 256, 256, 0, stream>>>(depths, gate, logdg, Lbits);

    k_sums<<<dim3(8, 128), 256, 0, stream>>>(projbf, patbf, logdg, lsum);
    k_retrieve<<<dim3(8, 64), 512, 0, stream>>>(projbf, patbf, logdg, lsum, maxwb, out);
    k_nd<<<(N_PAT + 255) / 256, 256, 0, stream>>>(depths, maxwb, Lbits, out + 262144);
}

// Round 2
// 538.479 us; speedup vs baseline: 1.6521x; 1.6521x over previous
//
#include <hip/hip_runtime.h>

#define N_PAT 100000
#define BDIM  1024
#define DDIM  256
#define CHUNKS 32
#define NTILE 1563   // ceil(100000/64)

typedef float f32x4 __attribute__((ext_vector_type(4)));
typedef short s16x8 __attribute__((ext_vector_type(8)));
typedef short s16x4 __attribute__((ext_vector_type(4)));

__device__ __forceinline__ unsigned short f2bf(float x) {
    unsigned int u = __float_as_uint(x);
    return (unsigned short)((u + 0x7FFFu + ((u >> 16) & 1u)) >> 16);
}
__device__ __forceinline__ float bf2f(unsigned short b) {
    return __uint_as_float(((unsigned int)b) << 16);
}
// Swizzled byte offsets (XOR 16B-slot swizzle within a row; T2/G4)
__device__ __forceinline__ int ofs128(int row, int byteInRow) {
    return row * 128 + (byteInRow ^ ((row & 7) << 4));
}
__device__ __forceinline__ int ofs512(int row, int byteInRow) {
    return row * 512 + (byteInRow ^ ((row & 7) << 4));
}
__device__ __forceinline__ void gl_lds16(void* lds, const void* g) {
    __builtin_amdgcn_global_load_lds(
        (const __attribute__((address_space(1))) void*)g,
        (__attribute__((address_space(3))) void*)lds, 16, 0, 0);
}

// ---------------- prep kernels ----------------
// patbf stored PRE-SWIZZLED: file slot s holds logical slot s^(n&7), so linear
// global_load_lds staging + ofs512 reads reconstruct the logical data (T21).
__global__ __launch_bounds__(256) void k_prep_pat(const float* __restrict__ pat,
                                                  unsigned short* __restrict__ patbf) {
    long total = (long)N_PAT * 32;
    long stride = (long)gridDim.x * blockDim.x;
    for (long g = (long)blockIdx.x * blockDim.x + threadIdx.x; g < total; g += stride) {
        int n = (int)(g >> 5), s = (int)(g & 31);
        const float4* src = (const float4*)(pat + (long)n * 256 + s * 8);
        float4 a = src[0], b = src[1];
        s16x8 o;
        o[0] = (short)f2bf(a.x); o[1] = (short)f2bf(a.y);
        o[2] = (short)f2bf(a.z); o[3] = (short)f2bf(a.w);
        o[4] = (short)f2bf(b.x); o[5] = (short)f2bf(b.y);
        o[6] = (short)f2bf(b.z); o[7] = (short)f2bf(b.w);
        *(s16x8*)(patbf + (long)n * 256 + (long)((s ^ (n & 7)) * 8)) = o;
    }
}

__global__ __launch_bounds__(256) void k_proj(const float* __restrict__ state,
                                              const float* __restrict__ W,
                                              unsigned short* __restrict__ projbf) {
    __shared__ float srow[DDIM];
    int b = blockIdx.x, t = threadIdx.x;
    srow[t] = state[b * DDIM + t];
    __syncthreads();
    const float4* s4 = (const float4*)srow;
    const float4* w4 = (const float4*)(W + (long)t * DDIM);
    float acc = 0.f;
#pragma unroll 8
    for (int k = 0; k < DDIM / 4; k++) {
        float4 sv = s4[k], wv = w4[k];
        acc += sv.x * wv.x + sv.y * wv.y + sv.z * wv.z + sv.w * wv.w;
    }
    // pre-swizzled store (row b)
    projbf[b * DDIM + ((t >> 3) ^ (b & 7)) * 8 + (t & 7)] = f2bf(acc);
}

__global__ __launch_bounds__(256) void k_prep_nd(const float* __restrict__ depths,
                                                 const float* __restrict__ gate,
                                                 float* __restrict__ logdg,
                                                 int* __restrict__ Lbits) {
    int n = blockIdx.x * 256 + threadIdx.x;
    float v = 0.f;
    if (n < N_PAT) {
        float d = depths[n], g = gate[n];
        logdg[n] = __logf(fmaxf(d, 1e-8f)) + __logf(fmaxf(g, 1e-8f));
        v = log1pf(d);
    }
#pragma unroll
    for (int m = 1; m <= 32; m <<= 1) v = fmaxf(v, __shfl_xor(v, m));
    if ((threadIdx.x & 63) == 0) atomicMax(Lbits, __float_as_int(v));
}

// ---------------- fused flash pass ----------------
// grid (8 rowblocks, 32 chunks), 512 threads (8 waves). Per block:
//  A (proj rowblock 128x256 bf16) resident in LDS, frags hoisted to regs.
//  loop over 64-wide n tiles (stride 32): stage P -> simsT MFMA -> e=exp ->
//  w-tile + colmax + l partials -> PV MFMA (O^T accumulate in regs).
//  3 raw barriers/tile; P(t+1) prefetch overlaps epilogue+PV.
__global__ __launch_bounds__(512, 2) void k_flash(
    const unsigned short* __restrict__ projbf,
    const unsigned short* __restrict__ patbf,
    const float* __restrict__ logdg,
    float* __restrict__ lsumg,
    int* __restrict__ colmax,
    float* __restrict__ outR) {
    __shared__ __align__(16) char sm[147456];
    char* Asm  = sm;             // 0..65536     [m=0..127] rows 512B
    char* Psm  = sm + 65536;     // ..98304      [n=0..63]  rows 512B
    char* PTsm = sm + 98304;     // ..131072     [d=0..255] rows 128B
    char* Wsm  = sm + 131072;    // ..147456     [m=0..127] rows 128B

    const int t = threadIdx.x, lane = t & 63, wid = t >> 6;
    const int lo = lane & 15, hi = lane >> 4;
    const int rb = blockIdx.x, chunk = blockIdx.y;
    const int mb = rb * 128;
    const int wm4 = wid >> 1, wn2 = wid & 1;   // sims roles: m-group 32, n-group 32
    const int wm2 = wid >> 2, wd4 = wid & 3;   // PV roles: m-half 64, d-quarter 64

    // prologue: stage A (8 x 16B/thread) and first P tile (4 x 16B/thread)
#pragma unroll
    for (int r = 0; r < 8; ++r) {
        int id = t + r * 512;
        int row = id >> 5, slot = id & 31;
        gl_lds16(Asm + id * 16, projbf + (long)(mb + row) * 256 + slot * 8);
    }
    {
        int n0 = chunk * 64;
#pragma unroll
        for (int r = 0; r < 4; ++r) {
            int id = t + r * 512;
            int row = id >> 5, slot = id & 31;
            int pn = n0 + row; if (pn >= N_PAT) pn = N_PAT - 1;
            gl_lds16(Psm + id * 16, patbf + (long)pn * 256 + slot * 8);
        }
    }
    asm volatile("s_waitcnt vmcnt(0)" ::: "memory");
    __builtin_amdgcn_s_barrier();

    // hoist A fragments (proj rows, the MFMA B-operand) to registers: 64 VGPR
    s16x8 af[2][8];
#pragma unroll
    for (int mf = 0; mf < 2; ++mf)
#pragma unroll
        for (int c = 0; c < 8; ++c)
            af[mf][c] = *(const s16x8*)(Asm + ofs512(wm4 * 32 + mf * 16 + lo, c * 64 + hi * 16));

    float lp[2] = {0.f, 0.f};
    f32x4 oacc[4][4];
#pragma unroll
    for (int i = 0; i < 4; ++i)
#pragma unroll
        for (int j = 0; j < 4; ++j) { oacc[i][j][0]=0.f; oacc[i][j][1]=0.f; oacc[i][j][2]=0.f; oacc[i][j][3]=0.f; }

    for (int tile = chunk; tile < NTILE; tile += CHUNKS) {
        int n0 = tile * 64;
        // ---- phase 1: transpose P->PT + simsT MFMA (reads Psm, Asm-regs)
#pragma unroll
        for (int i = 0; i < 4; ++i) {
            int kc8 = wid * 4 + i;
            s16x8 v = *(const s16x8*)(Psm + ofs512(lane, kc8 * 16));
#pragma unroll
            for (int e = 0; e < 8; ++e) {
                int d = kc8 * 8 + e;
                *(short*)(PTsm + ofs128(d, lane * 2)) = (short)v[e];
            }
        }
        f32x4 facc[2][2];
#pragma unroll
        for (int i = 0; i < 2; ++i)
#pragma unroll
            for (int j = 0; j < 2; ++j) { facc[i][j][0]=0.f; facc[i][j][1]=0.f; facc[i][j][2]=0.f; facc[i][j][3]=0.f; }
#pragma unroll
        for (int c = 0; c < 8; ++c) {
            s16x8 p0 = *(const s16x8*)(Psm + ofs512(wn2 * 32 + lo,      c * 64 + hi * 16));
            s16x8 p1 = *(const s16x8*)(Psm + ofs512(wn2 * 32 + 16 + lo, c * 64 + hi * 16));
            // S^T: C[n][m] = sum_k P[n][k] * proj[m][k]
            facc[0][0] = __builtin_amdgcn_mfma_f32_16x16x32_bf16(p0, af[0][c], facc[0][0], 0, 0, 0);
            facc[0][1] = __builtin_amdgcn_mfma_f32_16x16x32_bf16(p0, af[1][c], facc[0][1], 0, 0, 0);
            facc[1][0] = __builtin_amdgcn_mfma_f32_16x16x32_bf16(p1, af[0][c], facc[1][0], 0, 0, 0);
            facc[1][1] = __builtin_amdgcn_mfma_f32_16x16x32_bf16(p1, af[1][c], facc[1][1], 0, 0, 0);
        }
        asm volatile("s_waitcnt lgkmcnt(0)" ::: "memory");
        __builtin_amdgcn_s_barrier();
        // ---- phase 2: prefetch next P (overlaps epilogue+PV), epilogue
        if (tile + CHUNKS < NTILE) {
            int nn0 = (tile + CHUNKS) * 64;
#pragma unroll
            for (int r = 0; r < 4; ++r) {
                int id = t + r * 512;
                int row = id >> 5, slot = id & 31;
                int pn = nn0 + row; if (pn >= N_PAT) pn = N_PAT - 1;
                gl_lds16(Psm + id * 16, patbf + (long)pn * 256 + slot * 8);
            }
        }
        // epilogue: e = exp(S^T + logdg); facc[nf][mfB]: row n = wn2*32+nf*16+hi*4+r, col m = wm4*32+mfB*16+lo
#pragma unroll
        for (int nf = 0; nf < 2; ++nf) {
            int nbase = n0 + wn2 * 32 + nf * 16 + hi * 4;
            float4 lg4 = *(const float4*)(logdg + nbase);  // may over-read into l region: masked below
            float lg[4];
#pragma unroll
            for (int r = 0; r < 4; ++r) lg[r] = (nbase + r < N_PAT) ? ((const float*)&lg4)[r] : -1e30f;
            float ev[2][4];
#pragma unroll
            for (int mf = 0; mf < 2; ++mf)
#pragma unroll
                for (int r = 0; r < 4; ++r) {
                    float e = __expf(facc[nf][mf][r] + lg[r]);
                    ev[mf][r] = e;
                    lp[mf] += e;
                }
            // column max over m: reduce over lo lanes
            float mx[4];
#pragma unroll
            for (int r = 0; r < 4; ++r) {
                mx[r] = fmaxf(ev[0][r], ev[1][r]);
#pragma unroll
                for (int s = 1; s < 16; s <<= 1) mx[r] = fmaxf(mx[r], __shfl_xor(mx[r], s));
            }
            if (lo == 0) {
#pragma unroll
                for (int r = 0; r < 4; ++r) {
                    int nn = nbase + r;
                    if (nn < N_PAT) atomicMax(&colmax[nn], __float_as_int(mx[r]));
                }
            }
            // w-tile write: W[m][n] rows, 4 consecutive n -> b64 store
#pragma unroll
            for (int mf = 0; mf < 2; ++mf) {
                s16x4 wq;
#pragma unroll
                for (int r = 0; r < 4; ++r) wq[r] = (short)f2bf(ev[mf][r]);
                int m = wm4 * 32 + mf * 16 + lo;
                *(s16x4*)(Wsm + ofs128(m, (wn2 * 32 + nf * 16 + hi * 4) * 2)) = wq;
            }
        }
        asm volatile("s_waitcnt lgkmcnt(0)" ::: "memory");
        __builtin_amdgcn_s_barrier();
        // ---- phase 3: PV. O^T[d][m] += sum_n PT[d][n] * W[m][n]
#pragma unroll
        for (int ks = 0; ks < 2; ++ks) {
            int nb = ks * 64 + hi * 16;
            s16x8 pa[4], pb[4];
#pragma unroll
            for (int df = 0; df < 4; ++df)
                pa[df] = *(const s16x8*)(PTsm + ofs128(wd4 * 64 + df * 16 + lo, nb));
#pragma unroll
            for (int mf = 0; mf < 4; ++mf)
                pb[mf] = *(const s16x8*)(Wsm + ofs128(wm2 * 64 + mf * 16 + lo, nb));
#pragma unroll
            for (int df = 0; df < 4; ++df)
#pragma unroll
                for (int mf = 0; mf < 4; ++mf)
                    oacc[df][mf] = __builtin_amdgcn_mfma_f32_16x16x32_bf16(pa[df], pb[mf], oacc[df][mf], 0, 0, 0);
        }
        asm volatile("s_waitcnt vmcnt(0) lgkmcnt(0)" ::: "memory");
        __builtin_amdgcn_s_barrier();
    }

    // ---- output: transpose O^T through LDS, then line-dense atomics
#pragma unroll
    for (int df = 0; df < 4; ++df)
#pragma unroll
        for (int mf = 0; mf < 4; ++mf) {
            int m = wm2 * 64 + mf * 16 + lo;
            int d0 = wd4 * 64 + df * 16 + hi * 4;
            float4 v4 = make_float4(oacc[df][mf][0], oacc[df][mf][1], oacc[df][mf][2], oacc[df][mf][3]);
            *(float4*)(sm + m * 1024 + ((d0 * 4) ^ ((m & 7) << 4))) = v4;
        }
    asm volatile("s_waitcnt lgkmcnt(0)" ::: "memory");
    __builtin_amdgcn_s_barrier();
#pragma unroll
    for (int rr = 0; rr < 16; ++rr) {
        int m = rr * 8 + wid;
        float4 v4 = *(const float4*)(sm + m * 1024 + ((lane * 16) ^ ((m & 7) << 4)));
        float* dst = outR + (long)(mb + m) * 256 + lane * 4;
        atomicAdd(dst + 0, v4.x);
        atomicAdd(dst + 1, v4.y);
        atomicAdd(dst + 2, v4.z);
        atomicAdd(dst + 3, v4.w);
    }
    // l partials: reduce over hi groups, then atomic per column m
#pragma unroll
    for (int mf = 0; mf < 2; ++mf) {
        lp[mf] = fmaxf(lp[mf], 0.f);  // keep finite
        lp[mf] += __shfl_xor(lp[mf], 16);
        lp[mf] += __shfl_xor(lp[mf], 32);
    }
    if (lane < 16) {
#pragma unroll
        for (int mf = 0; mf < 2; ++mf)
            atomicAdd(&lsumg[mb + wm4 * 32 + mf * 16 + lane], lp[mf]);
    }
}

// ---------------- finalize ----------------
__global__ __launch_bounds__(256) void k_final(float* __restrict__ outR,
                                               const float* __restrict__ lsumg) {
    int g = blockIdx.x * 256 + threadIdx.x;  // 65536 float4s
    int m = g >> 6;
    float inv = 1.0f / lsumg[m];
    float4* p = (float4*)outR + g;
    float4 v = *p;
    v.x *= inv; v.y *= inv; v.z *= inv; v.w *= inv;
    *p = v;
}

__global__ void k_lmin(const float* __restrict__ lsumg, float* __restrict__ lminp) {
    __shared__ float red[16];
    int t = threadIdx.x;
    float v = lsumg[t];
#pragma unroll
    for (int s = 1; s <= 32; s <<= 1) v = fminf(v, __shfl_xor(v, s));
    if ((t & 63) == 0) red[t >> 6] = v;
    __syncthreads();
    if (t < 16) {
        v = red[t];
#pragma unroll
        for (int s = 1; s <= 8; s <<= 1) v = fminf(v, __shfl_xor(v, s));
        if (t == 0) *lminp = v;
    }
}

// safe columns: max_w <= colmax/lmin <= 0.09 < 0.1 -> reinforcement is exactly 0
__global__ __launch_bounds__(256) void k_nd(const float* __restrict__ depths,
                                            const int* __restrict__ colmax,
                                            const float* __restrict__ lminp,
                                            float* __restrict__ outD) {
    int n = blockIdx.x * 256 + threadIdx.x;
    if (n >= N_PAT) return;
    float cm = __int_as_float(colmax[n]);
    float lmin = *lminp;
    if (cm > 0.09f * lmin) return;  // k_fallback owns these
    outD[n] = depths[n];
}

// exact recompute for flagged columns (expected: none on typical data)
__global__ __launch_bounds__(256) void k_fallback(const unsigned short* __restrict__ projbf,
                                                  const float* __restrict__ depths,
                                                  const float* __restrict__ logdg,
                                                  const float* __restrict__ lsumg,
                                                  const int* __restrict__ colmax,
                                                  const float* __restrict__ lminp,
                                                  const int* __restrict__ Lbits,
                                                  const float* __restrict__ pat,
                                                  float* __restrict__ outD) {
    float lmin = *lminp;
    float L = __int_as_float(*Lbits);
    for (int n = blockIdx.x * 256 + threadIdx.x; n < N_PAT; n += 32 * 256) {
        float cm = __int_as_float(colmax[n]);
        if (cm <= 0.09f * lmin) continue;
        float ldgn = logdg[n];
        float mw = 0.f;
        for (int row = 0; row < BDIM; ++row) {
            float dot = 0.f;
            int r7 = row & 7;
            for (int s = 0; s < 32; ++s) {
                s16x8 v = *(const s16x8*)(projbf + (long)row * 256 + (s ^ r7) * 8);
                const float* p = pat + (long)n * 256 + s * 8;
#pragma unroll
                for (int e = 0; e < 8; ++e) dot += bf2f((unsigned short)v[e]) * p[e];
            }
            mw = fmaxf(mw, __expf(dot + ldgn) / lsumg[row]);
        }
        float d = depths[n];
        float dom = log1pf(d) / fmaxf(L, 1e-8f);
        outD[n] = d + ((mw > 0.1f) ? (0.01f * (1.0f - 0.7f * dom) * mw) : 0.f);
    }
}

// ---------------- launch ----------------
extern "C" void kernel_launch(void* const* d_in, const int* in_sizes, int n_in,
                              void* d_out, int out_size, void* d_ws, size_t ws_size,
                              hipStream_t stream) {
    const float* state  = (const float*)d_in[0];
    const float* W      = (const float*)d_in[1];
    const float* pat    = (const float*)d_in[2];
    const float* depths = (const float*)d_in[3];
    const float* gate   = (const float*)d_in[4];
    float* out = (float*)d_out;

    char* ws = (char*)d_ws;
    unsigned short* patbf  = (unsigned short*)ws;                  // 51,200,000
    unsigned short* projbf = (unsigned short*)(ws + 51200000);     //    524,288
    float* logdg = (float*)(ws + 51724288);                        //    400,000
    float* lsumg = (float*)(ws + 52124288);                        //      4,096
    int*   colmax = (int*)(ws + 52128384);                         //    400,000
    int*   Lbits = (int*)(ws + 52528384);                          //          4
    float* lminp = (float*)(ws + 52528388);                        //          4

    hipMemsetAsync(ws + 52124288, 0, 404112, stream);              // lsumg+colmax+Lbits+lmin
    hipMemsetAsync(d_out, 0, (size_t)out_size * 4, stream);

    k_prep_pat<<<2048, 256, 0, stream>>>(pat, patbf);
    k_proj<<<1024, 256, 0, stream>>>(state, W, projbf);
    k_prep_nd<<<(N_PAT + 255) / 256, 256, 0, stream>>>(depths, gate, logdg, Lbits);

    k_flash<<<dim3(8, CHUNKS), 512, 0, stream>>>(projbf, patbf, logdg, lsumg, colmax, out);

    k_final<<<256, 256, 0, stream>>>(out, lsumg);
    k_lmin<<<1, 1024, 0, stream>>>(lsumg, lminp);
    k_nd<<<(N_PAT + 255) / 256, 256, 0, stream>>>(depths, colmax, lminp, out + 262144);
    k_fallback<<<32, 256, 0, stream>>>(projbf, depths, logdg, lsumg, colmax, lminp, Lbits, pat, out + 262144);
}